// Round 6
// baseline (199.417 us; speedup 1.0000x reference)
//
#include <hip/hip_runtime.h>

namespace {

constexpr int T_LEN = 512;
constexpr float LOG2E = 1.4426950408889634f;

typedef _Float16 half4 __attribute__((ext_vector_type(4)));
typedef _Float16 half2v __attribute__((ext_vector_type(2)));
typedef float v4f __attribute__((ext_vector_type(4)));

__device__ __forceinline__ float fexp2(float a) {
#if __has_builtin(__builtin_amdgcn_exp2f)
    return __builtin_amdgcn_exp2f(a);
#else
    return exp2f(a);
#endif
}

__device__ __forceinline__ v4f mfma16h(half4 a, half4 b, v4f c) {
#if __has_builtin(__builtin_amdgcn_mfma_f32_16x16x16f16)
    return __builtin_amdgcn_mfma_f32_16x16x16f16(a, b, c, 0, 0, 0);
#else
    v4f d;
    asm volatile("v_mfma_f32_16x16x16_f16 %0, %1, %2, %3\n\ts_nop 7\n\ts_nop 7"
                 : "=v"(d) : "v"(a), "v"(b), "v"(c));
    return d;
#endif
}

__device__ __forceinline__ unsigned pk_f16(float a, float b) {
#if __has_builtin(__builtin_amdgcn_cvt_pkrtz)
    return __builtin_bit_cast(unsigned, __builtin_amdgcn_cvt_pkrtz(a, b));
#else
    half2v r; r[0] = (_Float16)a; r[1] = (_Float16)b;
    return __builtin_bit_cast(unsigned, r);
#endif
}

// one (row, element) gate evaluation + h update (identical math to R5)
__device__ __forceinline__ float gru_pair(float drp, float dzp, float dnp,
                                          float xt, float wihn, float bihn,
                                          float hp) {
    float Er = fexp2(drp);
    float Ez = fexp2(dzp);
    float pr = 1.0f + Er;
    float pz = 1.0f + Ez;
    float ip = __builtin_amdgcn_rcpf(pr * pz);
    float r  = ip * pz;                  // sigmoid(r-pre)
    float z  = ip * pr;                  // sigmoid(z-pre)
    float xn = __builtin_fmaf(xt, wihn, bihn);
    float v  = __builtin_fmaf(r, dnp, xn);
    float n  = __builtin_fmaf(-2.0f, __builtin_amdgcn_rcpf(1.0f + fexp2(v)), 1.0f);
    return __builtin_fmaf(z, hp - n, n); // (1-z)*n + z*h
}

__global__ __launch_bounds__(128) void gru_coop(
        const float* __restrict__ x,
        const float* __restrict__ W_ih,
        const float* __restrict__ W_hh,
        const float* __restrict__ b_ih,
        const float* __restrict__ b_hh,
        const float* __restrict__ fc_w,
        const float* __restrict__ fc_b,
        float* __restrict__ out) {
    const int lt = threadIdx.x;      // 0..127 (2 waves)
    const int w  = lt >> 6;          // wave id: 0 -> D-regs [0,1], 1 -> [2,3]
    const int L  = lt & 63;
    const int e  = L & 15;           // element column
    const int g  = L >> 4;           // row group; D rows jD..jD+3
    const int jD = g * 4;
    const int be = blockIdx.x * 16 + e;
    const int r0 = jD + 2 * w;       // the 2 gate rows this lane owns

    __shared__ unsigned hbuf[2][128];   // [buf][e*8 + rowpair] f16x2 h
    __shared__ float partialA[16];

    const float sR = -LOG2E;         // sigmoid scaling folded into weights
    const float sN = 2.0f * LOG2E;   // tanh scaling

    // ---- A fragments: W_hh rows (gate out j=e; k=jD..jD+3), scaled, f16 hi+lo
    half4 ar_hi, ar_lo, az_hi, az_lo, an_hi, an_lo;
#pragma unroll
    for (int i = 0; i < 4; ++i) {
        float wr = W_hh[(0  + e) * 16 + jD + i] * sR;
        float wz = W_hh[(16 + e) * 16 + jD + i] * sR;
        float wn = W_hh[(32 + e) * 16 + jD + i] * sN;
        _Float16 rh = (_Float16)wr; ar_hi[i] = rh; ar_lo[i] = (_Float16)(wr - (float)rh);
        _Float16 zh = (_Float16)wz; az_hi[i] = zh; az_lo[i] = (_Float16)(wz - (float)zh);
        _Float16 nh = (_Float16)wn; an_hi[i] = nh; an_lo[i] = (_Float16)(wn - (float)nh);
    }

    // ---- full 4-row constants (needed for MFMA C-operands)
    float wihr[4], wihz[4], biasr[4], biasz[4];
    v4f cn_const;
#pragma unroll
    for (int i = 0; i < 4; ++i) {
        int rj = jD + i;
        wihr[i]  = W_ih[rj]      * sR;
        wihz[i]  = W_ih[16 + rj] * sR;
        biasr[i] = (b_ih[rj]      + b_hh[rj])      * sR;
        biasz[i] = (b_ih[16 + rj] + b_hh[16 + rj]) * sR;
        cn_const[i] = b_hh[32 + rj] * sN;
    }
    // gate-only constants for this lane's 2 rows
    const float wihn0 = W_ih[32 + r0]     * sN;
    const float wihn1 = W_ih[32 + r0 + 1] * sN;
    const float bihn0 = b_ih[32 + r0]     * sN;
    const float bihn1 = b_ih[32 + r0 + 1] * sN;

    // ---- x timeline for this element (both waves load the same data; L1 absorbs)
    const float4* xb = (const float4*)(x + (size_t)be * T_LEN);
    float4 xc0 = xb[0], xc1 = xb[1], xc2 = xb[2], xc3 = xb[3];

    float hp0 = 0.f, hp1 = 0.f;          // this lane's 2 h rows (fp32 master)
    uint2 hz; hz.x = 0u; hz.y = 0u;
    half4 hf = __builtin_bit_cast(half4, hz);   // B-fragment (rows jD..jD+3, f16)

    const int wslot = e * 8 + 2 * g + w;  // write: rowpair 2g+w of elem e
    const int rslot = e * 8 + 2 * g;      // read: rowpairs 2g,2g+1 (b64)
    int buf = 0;

#pragma unroll 1
    for (int c = 0; c < T_LEN / 16; ++c) {
        float4 xn0, xn1, xn2, xn3;
        if (c + 1 < T_LEN / 16) {
            xn0 = xb[(c + 1) * 4 + 0];
            xn1 = xb[(c + 1) * 4 + 1];
            xn2 = xb[(c + 1) * 4 + 2];
            xn3 = xb[(c + 1) * 4 + 3];
        }
#pragma unroll
        for (int s = 0; s < 16; ++s) {
            float4 q4 = (s < 4) ? xc0 : (s < 8) ? xc1 : (s < 12) ? xc2 : xc3;
            float xt  = ((s & 3) == 0) ? q4.x : ((s & 3) == 1) ? q4.y
                      : ((s & 3) == 2) ? q4.z : q4.w;

            // C-inits (x-projection + biases)
            v4f cr, cz;
#pragma unroll
            for (int i = 0; i < 4; ++i) {
                cr[i] = __builtin_fmaf(xt, wihr[i], biasr[i]);
                cz[i] = __builtin_fmaf(xt, wihz[i], biasz[i]);
            }
            // matvec on MFMA pipe (redundant across the 2 waves — it's idle anyway)
            v4f dr = mfma16h(ar_hi, hf, cr);
            v4f dz = mfma16h(az_hi, hf, cz);
            v4f dn = mfma16h(an_hi, hf, cn_const);
            dr = mfma16h(ar_lo, hf, dr);
            dz = mfma16h(az_lo, hf, dz);
            dn = mfma16h(an_lo, hf, dn);

            // register-index work split: wave 0 -> rows jD,jD+1; wave 1 -> jD+2,jD+3
            float h0n, h1n;
            if (w == 0) {
                h0n = gru_pair(dr[0], dz[0], dn[0], xt, wihn0, bihn0, hp0);
                h1n = gru_pair(dr[1], dz[1], dn[1], xt, wihn1, bihn1, hp1);
            } else {
                h0n = gru_pair(dr[2], dz[2], dn[2], xt, wihn0, bihn0, hp0);
                h1n = gru_pair(dr[3], dz[3], dn[3], xt, wihn1, bihn1, hp1);
            }
            hp0 = h0n; hp1 = h1n;

            // exchange: write my 2 rows (f16x2), barrier, read my B-frag rows
            hbuf[buf][wslot] = pk_f16(h0n, h1n);
            asm volatile("s_waitcnt lgkmcnt(0)" ::: "memory");
            __builtin_amdgcn_s_barrier();        // raw barrier: no vmcnt drain,
            __builtin_amdgcn_sched_barrier(0);   // and no read hoisted above it
            uint2 hv = *reinterpret_cast<const uint2*>(&hbuf[buf][rslot]);
            hf = __builtin_bit_cast(half4, hv);  // rows jD..jD+3 in order
            buf ^= 1;
        }
        if (c + 1 < T_LEN / 16) { xc0 = xn0; xc1 = xn1; xc2 = xn2; xc3 = xn3; }
    }

    // ---- FC: out[be] = sum_r h[r]*fc_w[r] + fc_b
    float p = hp0 * fc_w[r0] + hp1 * fc_w[r0 + 1];
    p += __shfl_xor(p, 16, 64);
    p += __shfl_xor(p, 32, 64);      // per-wave partial (8 rows)
    if (w == 0 && L < 16) partialA[e] = p;
    __syncthreads();
    if (w == 1 && L < 16) out[be] = p + partialA[e] + fc_b[0];
}

} // namespace

extern "C" void kernel_launch(void* const* d_in, const int* in_sizes, int n_in,
                              void* d_out, int out_size, void* d_ws, size_t ws_size,
                              hipStream_t stream) {
    const float* x    = (const float*)d_in[0];
    const float* W_ih = (const float*)d_in[1];
    const float* W_hh = (const float*)d_in[2];
    const float* b_ih = (const float*)d_in[3];
    const float* b_hh = (const float*)d_in[4];
    const float* fc_w = (const float*)d_in[5];
    const float* fc_b = (const float*)d_in[6];
    float* out = (float*)d_out;

    const int B = out_size;               // 8192
    const int blocks = B / 16;            // 16 elements per 2-wave block
    gru_coop<<<blocks, 128, 0, stream>>>(x, W_ih, W_hh, b_ih, b_hh,
                                         fc_w, fc_b, out);
}

// Round 7
// 107.215 us; speedup vs baseline: 1.8600x; 1.8600x over previous
//
#include <hip/hip_runtime.h>

namespace {

constexpr int T_LEN = 512;
constexpr float LOG2E = 1.4426950408889634f;

typedef _Float16 half4 __attribute__((ext_vector_type(4)));
typedef _Float16 half2v __attribute__((ext_vector_type(2)));
typedef float v4f __attribute__((ext_vector_type(4)));

__device__ __forceinline__ float fexp2(float a) {
#if __has_builtin(__builtin_amdgcn_exp2f)
    return __builtin_amdgcn_exp2f(a);
#else
    return exp2f(a);
#endif
}

__device__ __forceinline__ v4f mfma16h(half4 a, half4 b, v4f c) {
#if __has_builtin(__builtin_amdgcn_mfma_f32_16x16x16f16)
    return __builtin_amdgcn_mfma_f32_16x16x16f16(a, b, c, 0, 0, 0);
#else
    v4f d;
    asm volatile("v_mfma_f32_16x16x16_f16 %0, %1, %2, %3\n\ts_nop 7\n\ts_nop 7"
                 : "=v"(d) : "v"(a), "v"(b), "v"(c));
    return d;
#endif
}

__device__ __forceinline__ unsigned pk_f16(float a, float b) {
#if __has_builtin(__builtin_amdgcn_cvt_pkrtz)
    return __builtin_bit_cast(unsigned, __builtin_amdgcn_cvt_pkrtz(a, b));
#else
    half2v r; r[0] = (_Float16)a; r[1] = (_Float16)b;
    return __builtin_bit_cast(unsigned, r);
#endif
}

template<int OFF>
__device__ __forceinline__ unsigned ds_swz_u(unsigned v) {
    return (unsigned)__builtin_amdgcn_ds_swizzle((int)v, OFF);
}

// one (row, element) gate evaluation + h update (identical math to R5)
__device__ __forceinline__ float gru_pair(float drp, float dzp, float dnp,
                                          float xt, float wihn, float bihn,
                                          float hp) {
    float Er = fexp2(drp);
    float Ez = fexp2(dzp);
    float pr = 1.0f + Er;
    float pz = 1.0f + Ez;
    float ip = __builtin_amdgcn_rcpf(pr * pz);
    float r  = ip * pz;                  // sigmoid(r-pre)
    float z  = ip * pr;                  // sigmoid(z-pre)
    float xn = __builtin_fmaf(xt, wihn, bihn);
    float v  = __builtin_fmaf(r, dnp, xn);
    float n  = __builtin_fmaf(-2.0f, __builtin_amdgcn_rcpf(1.0f + fexp2(v)), 1.0f);
    return __builtin_fmaf(z, hp - n, n); // (1-z)*n + z*h
}

__global__ __launch_bounds__(64) void gru_mfma8(
        const float* __restrict__ x,
        const float* __restrict__ W_ih,
        const float* __restrict__ W_hh,
        const float* __restrict__ b_ih,
        const float* __restrict__ b_hh,
        const float* __restrict__ fc_w,
        const float* __restrict__ fc_b,
        float* __restrict__ out) {
    const int L  = threadIdx.x;      // 0..63
    const int e  = L & 15;           // MFMA column (cols e and e+8 duplicate)
    const int g  = L >> 4;           // row group; D rows jD..jD+3 of col e
    const int jD = g * 4;
    const int ehi  = (e >> 3) & 1;   // 0: this lane gates rows jD,jD+1 ; 1: jD+2,jD+3
    const int ecol = e & 7;          // real batch column within the group
    const int be   = blockIdx.x * 8 + ecol;
    const int r0   = jD + 2 * ehi;   // first of the 2 gate rows this lane owns

    const float sR = -LOG2E;         // sigmoid scaling folded into weights
    const float sN = 2.0f * LOG2E;   // tanh scaling

    // ---- A fragments: W_hh rows (gate out m = e, full 0..15; k = jD..jD+3),
    //      scaled, f16 hi + f16 residual  (same for both column halves)
    half4 ar_hi, ar_lo, az_hi, az_lo, an_hi, an_lo;
#pragma unroll
    for (int i = 0; i < 4; ++i) {
        float wr = W_hh[(0  + e) * 16 + jD + i] * sR;
        float wz = W_hh[(16 + e) * 16 + jD + i] * sR;
        float wn = W_hh[(32 + e) * 16 + jD + i] * sN;
        _Float16 rh = (_Float16)wr; ar_hi[i] = rh; ar_lo[i] = (_Float16)(wr - (float)rh);
        _Float16 zh = (_Float16)wz; az_hi[i] = zh; az_lo[i] = (_Float16)(wz - (float)zh);
        _Float16 nh = (_Float16)wn; an_hi[i] = nh; an_lo[i] = (_Float16)(wn - (float)nh);
    }

    // ---- per-D-row constants (all 4 rows jD..jD+3: needed for MFMA C operands)
    float wihr[4], wihz[4], biasr[4], biasz[4];
    v4f cn_const;
#pragma unroll
    for (int i = 0; i < 4; ++i) {
        int rj = jD + i;
        wihr[i]  = W_ih[rj]      * sR;
        wihz[i]  = W_ih[16 + rj] * sR;
        biasr[i] = (b_ih[rj]      + b_hh[rj])      * sR;
        biasz[i] = (b_ih[16 + rj] + b_hh[16 + rj]) * sR;
        cn_const[i] = b_hh[32 + rj] * sN;
    }
    // gate-only constants for this lane's 2 rows
    const float wihn0 = W_ih[32 + r0]     * sN;
    const float wihn1 = W_ih[32 + r0 + 1] * sN;
    const float bihn0 = b_ih[32 + r0]     * sN;
    const float bihn1 = b_ih[32 + r0 + 1] * sN;

    // ---- x timeline for this column (lanes e and e+8 load identical addresses)
    const float4* xb = (const float4*)(x + (size_t)be * T_LEN);
    float4 xc0 = xb[0], xc1 = xb[1], xc2 = xb[2], xc3 = xb[3];

    float hp0 = 0.f, hp1 = 0.f;          // this lane's 2 h rows (fp32 master)
    uint2 hz; hz.x = 0u; hz.y = 0u;
    half4 hf = __builtin_bit_cast(half4, hz);   // B-frag: rows jD..jD+3 (f16)

#pragma unroll 1
    for (int c = 0; c < T_LEN / 16; ++c) {
        float4 xn0, xn1, xn2, xn3;
        if (c + 1 < T_LEN / 16) {
            xn0 = xb[(c + 1) * 4 + 0];
            xn1 = xb[(c + 1) * 4 + 1];
            xn2 = xb[(c + 1) * 4 + 2];
            xn3 = xb[(c + 1) * 4 + 3];
        }
#pragma unroll
        for (int s = 0; s < 16; ++s) {
            float4 q4 = (s < 4) ? xc0 : (s < 8) ? xc1 : (s < 12) ? xc2 : xc3;
            float xt  = ((s & 3) == 0) ? q4.x : ((s & 3) == 1) ? q4.y
                      : ((s & 3) == 2) ? q4.z : q4.w;

            // C-inits (x-projection + biases) for all 4 D rows
            v4f cr, cz;
#pragma unroll
            for (int i = 0; i < 4; ++i) {
                cr[i] = __builtin_fmaf(xt, wihr[i], biasr[i]);
                cz[i] = __builtin_fmaf(xt, wihz[i], biasz[i]);
            }
            // matvec on MFMA pipe: 2 MFMAs per gate (f16 hi+lo split)
            v4f dr = mfma16h(ar_hi, hf, cr);
            v4f dz = mfma16h(az_hi, hf, cz);
            v4f dn = mfma16h(an_hi, hf, cn_const);
            dr = mfma16h(ar_lo, hf, dr);
            dz = mfma16h(az_lo, hf, dz);
            dn = mfma16h(an_lo, hf, dn);

            // column-duplication work split: e<8 -> regs [0,1]; e>=8 -> regs [2,3]
            float d_r0 = ehi ? dr[2] : dr[0];
            float d_r1 = ehi ? dr[3] : dr[1];
            float d_z0 = ehi ? dz[2] : dz[0];
            float d_z1 = ehi ? dz[3] : dz[1];
            float d_n0 = ehi ? dn[2] : dn[0];
            float d_n1 = ehi ? dn[3] : dn[1];

            float h0n = gru_pair(d_r0, d_z0, d_n0, xt, wihn0, bihn0, hp0);
            float h1n = gru_pair(d_r1, d_z1, d_n1, xt, wihn1, bihn1, hp1);
            hp0 = h0n; hp1 = h1n;

            // reassemble B-frag: my rowpair + partner's rowpair (xor 8, intra-wave)
            unsigned mine = pk_f16(h0n, h1n);
            unsigned oth  = ds_swz_u<0x201F>(mine);   // BitMode xor-8 swizzle
            uint2 hv;
            hv.x = ehi ? oth  : mine;    // rows jD, jD+1
            hv.y = ehi ? mine : oth;     // rows jD+2, jD+3
            hf = __builtin_bit_cast(half4, hv);
        }
        if (c + 1 < T_LEN / 16) { xc0 = xn0; xc1 = xn1; xc2 = xn2; xc3 = xn3; }
    }

    // ---- FC: coset {L^8, L^16, L^32} covers all 16 rows of col ecol exactly once
    float p = hp0 * fc_w[r0] + hp1 * fc_w[r0 + 1];
    p += __shfl_xor(p, 8, 64);
    p += __shfl_xor(p, 16, 64);
    p += __shfl_xor(p, 32, 64);
    if (L < 8) out[blockIdx.x * 8 + L] = p + fc_b[0];
}

} // namespace

extern "C" void kernel_launch(void* const* d_in, const int* in_sizes, int n_in,
                              void* d_out, int out_size, void* d_ws, size_t ws_size,
                              hipStream_t stream) {
    const float* x    = (const float*)d_in[0];
    const float* W_ih = (const float*)d_in[1];
    const float* W_hh = (const float*)d_in[2];
    const float* b_ih = (const float*)d_in[3];
    const float* b_hh = (const float*)d_in[4];
    const float* fc_w = (const float*)d_in[5];
    const float* fc_b = (const float*)d_in[6];
    float* out = (float*)d_out;

    const int B = out_size;               // 8192
    const int blocks = B / 8;             // 8 elements per 1-wave block (cols duplicated)
    gru_mfma8<<<blocks, 64, 0, stream>>>(x, W_ih, W_hh, b_ih, b_hh,
                                         fc_w, fc_b, out);
}